// Round 1
// baseline (3934.250 us; speedup 1.0000x reference)
//
#include <hip/hip_runtime.h>

#define N_    64
#define C_    64
#define T_    300
#define V_    25
#define IC_   16
#define TV_   7500      // T*V
#define CTV_  480000    // C*T*V  (per-n x slice)
#define FNS_  120000    // IC*T*V (per-n f slice)
#define NPOS_ 480000    // N*T*V thread positions for conv kernels
#define TOTAL_ 30720000 // N*C*T*V

// ---------------- A_mix: Chebyshev mix + column softmax ----------------
__global__ void amix_kernel(const float* __restrict__ A, const float* __restrict__ w,
                            float* __restrict__ amix) {
    int tid = threadIdx.x;
    if (tid >= 75) return;
    int s = tid / 25, col = tid % 25;
    const float* As = A + s * 625;
    float av[25], ch4[25];
#pragma unroll
    for (int r = 0; r < 25; ++r) {
        float a = As[r * 25 + col];
        float a2 = a * a;
        float eye = (r == col) ? 1.f : 0.f;
        av[r] = a;
        ch4[r] = 8.f * a2 * a2 - 8.f * a2 + eye;
    }
    float m = -1e30f;
#pragma unroll
    for (int r = 0; r < 25; ++r) m = fmaxf(m, ch4[r] * (1.f / 25.f));
    float e[25];
    float sum = 0.f;
#pragma unroll
    for (int r = 0; r < 25; ++r) { e[r] = __expf(ch4[r] * (1.f / 25.f) - m); sum += e[r]; }
    float inv = 1.f / sum;
    float w0 = w[0], w1 = w[1], w2 = w[2], w3 = w[3], w4 = w[4];
#pragma unroll
    for (int r = 0; r < 25; ++r) {
        float a = av[r], a2 = a * a;
        float eye = (r == col) ? 1.f : 0.f;
        amix[s * 625 + r * 25 + col] =
            w0 * a + w1 * (e[r] * inv) + w2 * ch4[r] +
            w3 * (4.f * a2 * a - 3.f * a) + w4 * (2.f * a2 - eye);
    }
}

// ---------------- conv1x1 pair: f1,f2 = W1*x+b1, W2*x+b2 ----------------
__global__ __launch_bounds__(256) void conv1x1_pair(
    const float* __restrict__ x,
    const float* __restrict__ w1, const float* __restrict__ b1,
    const float* __restrict__ w2, const float* __restrict__ b2,
    float* __restrict__ f1, float* __restrict__ f2) {
    __shared__ float ws1[IC_ * C_], ws2[IC_ * C_];
    int tid = threadIdx.x;
    for (int j = tid; j < IC_ * C_; j += 256) { ws1[j] = w1[j]; ws2[j] = w2[j]; }
    __syncthreads();
    int p = blockIdx.x * 256 + tid;     // 480000 positions, grid exact
    int n = p / TV_;
    int r = p - n * TV_;
    const float* xp = x + n * CTV_ + r;
    float acc1[IC_], acc2[IC_];
#pragma unroll
    for (int o = 0; o < IC_; ++o) { acc1[o] = 0.f; acc2[o] = 0.f; }
    for (int c = 0; c < C_; ++c) {
        float xv = xp[c * TV_];
#pragma unroll
        for (int o = 0; o < IC_; ++o) {
            acc1[o] += xv * ws1[o * C_ + c];
            acc2[o] += xv * ws2[o * C_ + c];
        }
    }
    float* f1p = f1 + n * FNS_ + r;
    float* f2p = f2 + n * FNS_ + r;
#pragma unroll
    for (int o = 0; o < IC_; ++o) {
        f1p[o * TV_] = acc1[o] + b1[o];
        f2p[o * TV_] = acc2[o] + b2[o];
    }
}

// ---------------- conv9x1 pair (9-tap over T, pad 4) ----------------
__global__ __launch_bounds__(256) void conv9x1_pair(
    const float* __restrict__ x,
    const float* __restrict__ w1, const float* __restrict__ b1,
    const float* __restrict__ w2, const float* __restrict__ b2,
    float* __restrict__ f1, float* __restrict__ f2) {
    // weights staged per c-half: [k][c32][o] = 9*32*16 floats each
    __shared__ float ws1[9 * 32 * IC_], ws2[9 * 32 * IC_];
    int tid = threadIdx.x;
    int p = blockIdx.x * 256 + tid;
    int n = p / TV_;
    int r = p - n * TV_;
    int t = r / V_;
    int v = r - t * V_;
    const float* xp = x + n * CTV_ + v;
    float acc1[IC_], acc2[IC_];
#pragma unroll
    for (int o = 0; o < IC_; ++o) { acc1[o] = 0.f; acc2[o] = 0.f; }

    for (int half = 0; half < 2; ++half) {
        __syncthreads();   // protect LDS from previous half's readers
        for (int j = tid; j < 9 * 32 * IC_; j += 256) {
            int k = j >> 9;            // /512
            int c = (j >> 4) & 31;
            int o = j & 15;
            int src = (o * C_ + half * 32 + c) * 9 + k;
            ws1[j] = w1[src];
            ws2[j] = w2[src];
        }
        __syncthreads();
        for (int c = 0; c < 32; ++c) {
            const float* xc = xp + (half * 32 + c) * TV_;
            float xv[9];
#pragma unroll
            for (int k = 0; k < 9; ++k) {
                int tk = t + k - 4;
                xv[k] = (tk >= 0 && tk < T_) ? xc[tk * V_] : 0.f;
            }
#pragma unroll
            for (int k = 0; k < 9; ++k) {
                const float* wl1 = &ws1[(k * 32 + c) * IC_];
                const float* wl2 = &ws2[(k * 32 + c) * IC_];
                float xk = xv[k];
#pragma unroll
                for (int o = 0; o < IC_; ++o) {
                    acc1[o] += xk * wl1[o];
                    acc2[o] += xk * wl2[o];
                }
            }
        }
    }
    float* f1p = f1 + n * FNS_ + r;
    float* f2p = f2 + n * FNS_ + r;
#pragma unroll
    for (int o = 0; o < IC_; ++o) {
        f1p[o * TV_] = acc1[o] + b1[o];
        f2p[o * TV_] = acc2[o] + b2[o];
    }
}

// ---------------- gram partial: S_part[n,v1,v2] over 960 contraction rows ----------------
__global__ __launch_bounds__(256) void gram_partial(
    const float* __restrict__ f1, const float* __restrict__ f2, float* __restrict__ part) {
    __shared__ float t1[64 * 25], t2[64 * 25];
    int n = blockIdx.x, pr = blockIdx.y;   // pr in [0,5)
    int tid = threadIdx.x;
    const float* f1n = f1 + n * FNS_ + pr * 960 * 25;
    const float* f2n = f2 + n * FNS_ + pr * 960 * 25;
    int va0 = tid / 25, vb0 = tid % 25;
    int va1 = (tid + 256) / 25, vb1 = (tid + 256) % 25;
    int va2 = (tid + 512) / 25, vb2 = (tid + 512) % 25;
    float acc0 = 0.f, acc1 = 0.f, acc2 = 0.f;
    for (int tile = 0; tile < 15; ++tile) {
        __syncthreads();
        for (int j = tid; j < 1600; j += 256) {
            t1[j] = f1n[tile * 1600 + j];
            t2[j] = f2n[tile * 1600 + j];
        }
        __syncthreads();
#pragma unroll 8
        for (int rr = 0; rr < 64; ++rr) {
            const float* r1 = &t1[rr * 25];
            const float* r2 = &t2[rr * 25];
            acc0 += r1[va0] * r2[vb0];
            acc1 += r1[va1] * r2[vb1];
            acc2 += r1[va2] * r2[vb2];   // safe in-bounds LDS read even when unused
        }
    }
    float* pp = part + (pr * 64 + n) * 625;
    pp[tid] = acc0;
    pp[tid + 256] = acc1;
    if (tid < 113) pp[tid + 512] = acc2;
}

// ---------------- gram finalize: sum parts, scale, column softmax ----------------
__global__ __launch_bounds__(256) void gram_finalize(
    const float* __restrict__ part, float* __restrict__ S) {
    __shared__ float sm[625];
    int n = blockIdx.x, tid = threadIdx.x;
    for (int q = tid; q < 625; q += 256) {
        float s = 0.f;
#pragma unroll
        for (int p = 0; p < 5; ++p) s += part[(p * 64 + n) * 625 + q];
        sm[q] = s * (1.f / 4800.f);
    }
    __syncthreads();
    if (tid < 25) {
        int col = tid;
        float m = -1e30f;
#pragma unroll
        for (int r = 0; r < 25; ++r) m = fmaxf(m, sm[r * 25 + col]);
        float e[25];
        float sum = 0.f;
#pragma unroll
        for (int r = 0; r < 25; ++r) { e[r] = __expf(sm[r * 25 + col] - m); sum += e[r]; }
        float inv = 1.f / sum;
#pragma unroll
        for (int r = 0; r < 25; ++r) S[n * 625 + r * 25 + col] = e[r] * inv;
    }
}

// ---------------- fused: Ai build + z = x@Ai + y += d_w@z + d_b ----------------
__global__ __launch_bounds__(256) void fused_zd(
    const float* __restrict__ x, const float* __restrict__ amix,
    const float* __restrict__ Sab, const float* __restrict__ St, const float* __restrict__ Sst,
    const float* __restrict__ wts, const float* __restrict__ dw, const float* __restrict__ db,
    float* __restrict__ y, int first) {
    __shared__ float xs[64 * 75];   // [c][3t*25v]
    __shared__ float zs[64 * 75];
    __shared__ float aw[625];
    __shared__ float dws[4096];
    int n = blockIdx.y;
    int t0 = blockIdx.x * 3;
    int tid = threadIdx.x;
    float w5 = wts[5], w6 = wts[6], w7 = wts[7];
    for (int j = tid; j < 625; j += 256)
        aw[j] = amix[j] + w5 * Sab[n * 625 + j] + w6 * St[n * 625 + j] + w7 * Sst[n * 625 + j];
    for (int j = tid; j < 4096; j += 256) dws[j] = dw[j];
    const float* xb = x + n * CTV_ + t0 * V_;
    for (int j = tid; j < 4800; j += 256) {
        int c = j / 75, q = j - c * 75;
        xs[j] = xb[c * TV_ + q];
    }
    __syncthreads();
    for (int j = tid; j < 4800; j += 256) {
        int c = j / 75, q = j - c * 75;
        int tt = q / 25, v = q - tt * 25;
        float acc = 0.f;
        const float* xr = &xs[c * 75 + tt * 25];
#pragma unroll
        for (int vp = 0; vp < 25; ++vp) acc += xr[vp] * aw[vp * 25 + v];
        zs[j] = acc;
    }
    __syncthreads();
    float* yb = y + n * CTV_ + t0 * V_;
    for (int j = tid; j < 4800; j += 256) {
        int o = j / 75, q = j - o * 75;
        float acc = db[o];
        const float* dr = &dws[o * 64];
#pragma unroll 16
        for (int c = 0; c < 64; ++c) acc += dr[c] * zs[c * 75 + q];
        float* yp = &yb[o * TV_ + q];
        if (first) *yp = acc;
        else       *yp += acc;
    }
}

// ---------------- BN reduce: per-channel sum / sumsq ----------------
__global__ __launch_bounds__(256) void bn_reduce(const float* __restrict__ y,
                                                 float* __restrict__ stats) {
    int o = blockIdx.x;       // channel
    int partn = blockIdx.y;   // n-range [8p, 8p+8)
    int tid = threadIdx.x;
    float s = 0.f, s2 = 0.f;
    for (int nn = partn * 8; nn < partn * 8 + 8; ++nn) {
        const float* yp = y + (nn * C_ + o) * TV_;
        for (int j = tid; j < TV_; j += 256) {
            float v = yp[j];
            s += v;
            s2 += v * v;
        }
    }
    for (int off = 32; off > 0; off >>= 1) {
        s += __shfl_down(s, off, 64);
        s2 += __shfl_down(s2, off, 64);
    }
    __shared__ float ls[8];
    int wave = tid >> 6, lane = tid & 63;
    if (lane == 0) { ls[wave] = s; ls[4 + wave] = s2; }
    __syncthreads();
    if (tid == 0) {
        atomicAdd(&stats[o], ls[0] + ls[1] + ls[2] + ls[3]);
        atomicAdd(&stats[64 + o], ls[4] + ls[5] + ls[6] + ls[7]);
    }
}

// ---------------- BN apply + residual + relu (in place on y) ----------------
__global__ __launch_bounds__(256) void bn_final(
    const float* __restrict__ x, const float* __restrict__ stats,
    const float* __restrict__ bnw, const float* __restrict__ bnb,
    float* __restrict__ y) {
    int pi = blockIdx.x * 256 + threadIdx.x;   // grid exact: 30,720,000 / 256
    int o = (pi / TV_) & 63;
    const float cnt = (float)(N_ * TV_);
    float mu = stats[o] / cnt;
    float var = stats[64 + o] / cnt - mu * mu;
    float inv = rsqrtf(var + 1e-5f);
    float val = (y[pi] - mu) * inv * bnw[o] + bnb[o] + x[pi];
    y[pi] = fmaxf(val, 0.f);
}

extern "C" void kernel_launch(void* const* d_in, const int* in_sizes, int n_in,
                              void* d_out, int out_size, void* d_ws, size_t ws_size,
                              hipStream_t stream) {
    (void)in_sizes; (void)n_in; (void)out_size; (void)ws_size;
    const float* x     = (const float*)d_in[0];
    const float* wts   = (const float*)d_in[1];
    const float* A     = (const float*)d_in[2];
    const float* a_w   = (const float*)d_in[3];
    const float* a_b   = (const float*)d_in[4];
    const float* b_w   = (const float*)d_in[5];
    const float* b_b   = (const float*)d_in[6];
    const float* d_wp  = (const float*)d_in[7];
    const float* d_bp  = (const float*)d_in[8];
    const float* t1_w  = (const float*)d_in[9];
    const float* t1_b  = (const float*)d_in[10];
    const float* t2_w  = (const float*)d_in[11];
    const float* t2_b  = (const float*)d_in[12];
    const float* st11_w1 = (const float*)d_in[13];
    const float* st11_w9 = (const float*)d_in[14];
    const float* st11_b  = (const float*)d_in[15];
    const float* st12_w1 = (const float*)d_in[16];
    const float* st12_w9 = (const float*)d_in[17];
    const float* st12_b  = (const float*)d_in[18];
    const float* bn_w  = (const float*)d_in[19];
    const float* bn_b  = (const float*)d_in[20];
    float* out = (float*)d_out;

    char* ws = (char*)d_ws;
    float* amix  = (float*)(ws);              // 1875 floats
    float* stats = (float*)(ws + 8192);       // 128 floats
    float* S     = (float*)(ws + 16384);      // 3 * 40000 floats
    float* part  = (float*)(ws + 524288);     // 200000 floats
    float* f1    = (float*)(ws + 2097152);    // 7,680,000 floats
    float* f2    = (float*)(ws + 33554432);   // 7,680,000 floats

    amix_kernel<<<1, 128, 0, stream>>>(A, wts, amix);
    hipMemsetAsync(stats, 0, 512, stream);

    auto run_pair = [&](bool nine, const float* w1, const float* bb1,
                        const float* w2, const float* bb2, float* Sdst) {
        if (nine)
            conv9x1_pair<<<1875, 256, 0, stream>>>(x, w1, bb1, w2, bb2, f1, f2);
        else
            conv1x1_pair<<<1875, 256, 0, stream>>>(x, w1, bb1, w2, bb2, f1, f2);
        gram_partial<<<dim3(64, 5), 256, 0, stream>>>(f1, f2, part);
        gram_finalize<<<64, 256, 0, stream>>>(part, Sdst);
    };

    for (int i = 0; i < 3; ++i) {
        run_pair(false, a_w + i * 1024, a_b + i * 16, b_w + i * 1024, b_b + i * 16, S);
        run_pair(true,  t1_w + i * 9216, t1_b + i * 16, t2_w + i * 9216, t2_b + i * 16, S + 40000);
        if (i == 1) {
            run_pair(true, st11_w9, st11_b + 16, st12_w9, st12_b + 16, S + 80000);
        } else {
            int j = (i == 0) ? 0 : 1;
            run_pair(false, st11_w1 + j * 1024, st11_b + i * 16,
                     st12_w1 + j * 1024, st12_b + i * 16, S + 80000);
        }
        fused_zd<<<dim3(100, 64), 256, 0, stream>>>(
            x, amix + i * 625, S, S + 40000, S + 80000, wts,
            d_wp + i * 4096, d_bp + i * 64, out, (i == 0) ? 1 : 0);
    }

    bn_reduce<<<dim3(64, 8), 256, 0, stream>>>(out, stats);
    bn_final<<<120000, 256, 0, stream>>>(x, stats, bn_w, bn_b, out);
}

// Round 2
// 3203.759 us; speedup vs baseline: 1.2280x; 1.2280x over previous
//
#include <hip/hip_runtime.h>

#define N_    64
#define C_    64
#define T_    300
#define V_    25
#define IC_   16
#define TV_   7500      // T*V
#define CTV_  480000    // C*T*V  (per-n x slice)
#define FNS_  120000    // IC*T*V (per-n f slice)

typedef __attribute__((ext_vector_type(8))) short short8;
typedef __attribute__((ext_vector_type(4))) float f32x4;

static __device__ inline short f2bf(float f) {
    unsigned u = __float_as_uint(f);
    unsigned r = (u + 0x7fff + ((u >> 16) & 1)) >> 16;
    return (short)r;
}

// ---------------- A_mix: Chebyshev mix + column softmax ----------------
__global__ void amix_kernel(const float* __restrict__ A, const float* __restrict__ w,
                            float* __restrict__ amix) {
    int tid = threadIdx.x;
    if (tid >= 75) return;
    int s = tid / 25, col = tid % 25;
    const float* As = A + s * 625;
    float av[25], ch4[25];
#pragma unroll
    for (int r = 0; r < 25; ++r) {
        float a = As[r * 25 + col];
        float a2 = a * a;
        float eye = (r == col) ? 1.f : 0.f;
        av[r] = a;
        ch4[r] = 8.f * a2 * a2 - 8.f * a2 + eye;
    }
    float m = -1e30f;
#pragma unroll
    for (int r = 0; r < 25; ++r) m = fmaxf(m, ch4[r] * (1.f / 25.f));
    float e[25];
    float sum = 0.f;
#pragma unroll
    for (int r = 0; r < 25; ++r) { e[r] = __expf(ch4[r] * (1.f / 25.f) - m); sum += e[r]; }
    float inv = 1.f / sum;
    float w0 = w[0], w1 = w[1], w2 = w[2], w3 = w[3], w4 = w[4];
#pragma unroll
    for (int r = 0; r < 25; ++r) {
        float a = av[r], a2 = a * a;
        float eye = (r == col) ? 1.f : 0.f;
        amix[s * 625 + r * 25 + col] =
            w0 * a + w1 * (e[r] * inv) + w2 * ch4[r] +
            w3 * (4.f * a2 * a - 3.f * a) + w4 * (2.f * a2 - eye);
    }
}

// ---------------- weight prep: pack pair weights into A-fragment order, bf16 ----------------
// wpk[((kk*2+half)*64 + lane)*8 + j] = W_half[o = lane&15][c = K&63][k = K>>6],
// K = kk*32 + ((lane>>4)<<3) + j.  W layout: w[(o*64+c)*taps + k].
__global__ void wprep(const float* __restrict__ w1, const float* __restrict__ w2,
                      short* __restrict__ wpk, int taps) {
    int idx = blockIdx.x * 256 + threadIdx.x;
    if (idx >= taps * 2048) return;
    int j = idx & 7;
    int l = (idx >> 3) & 63;
    int half = (idx >> 9) & 1;
    int kk = idx >> 10;
    int K = kk * 32 + ((l >> 4) << 3) + j;
    int c = K & 63, k = K >> 6;
    int o = l & 15;
    const float* w = half ? w2 : w1;
    wpk[idx] = f2bf(w[(o * 64 + c) * taps + k]);
}

// ---------------- conv pair via MFMA: f{1,2}[o,p] = sum_{c,k} W[o,c,k] x[c, p+(k-t/2)*25] ----------------
template <int TAPS>
__global__ __launch_bounds__(256) void conv_mfma(
    const float* __restrict__ x, const short* __restrict__ wpk,
    const float* __restrict__ b1, const float* __restrict__ b2,
    float* __restrict__ f1, float* __restrict__ f2) {
    constexpr int HALO = (TAPS / 2) * 25;
    constexpr int ROWS = 128 + 2 * HALO;
    __shared__ __align__(16) short xs[ROWS * 72];   // [row][c] bf16, stride 72 (36 words)
    int tid = threadIdx.x;
    int n = blockIdx.y;
    int p0 = blockIdx.x * 128;
    const float* xn = x + n * CTV_;
    for (int jj = tid; jj < 64 * ROWS; jj += 256) {
        int c = jj / ROWS;
        int rr = jj - c * ROWS;
        int pp = p0 - HALO + rr;
        float v = (pp >= 0 && pp < TV_) ? xn[c * TV_ + pp] : 0.f;
        xs[rr * 72 + c] = f2bf(v);
    }
    __syncthreads();

    int wave = tid >> 6, lane = tid & 63;
    int q = lane >> 4, m = lane & 15;
    int pw = wave * 32;
    f32x4 acc[2][2];
#pragma unroll
    for (int h = 0; h < 2; ++h)
#pragma unroll
        for (int nt = 0; nt < 2; ++nt) acc[h][nt] = (f32x4)(0.f);

#pragma unroll
    for (int kk = 0; kk < 2 * TAPS; ++kk) {
        int k = kk >> 1;
        int c0 = (kk & 1) * 32;
        short8 a0 = *(const short8*)(wpk + ((kk * 2 + 0) * 64 + lane) * 8);
        short8 a1 = *(const short8*)(wpk + ((kk * 2 + 1) * 64 + lane) * 8);
        int rbase = HALO + pw + m + (k - TAPS / 2) * 25;
        short8 bf0 = *(const short8*)(xs + rbase * 72 + c0 + q * 8);
        short8 bf1 = *(const short8*)(xs + (rbase + 16) * 72 + c0 + q * 8);
        acc[0][0] = __builtin_amdgcn_mfma_f32_16x16x32_bf16(a0, bf0, acc[0][0], 0, 0, 0);
        acc[0][1] = __builtin_amdgcn_mfma_f32_16x16x32_bf16(a0, bf1, acc[0][1], 0, 0, 0);
        acc[1][0] = __builtin_amdgcn_mfma_f32_16x16x32_bf16(a1, bf0, acc[1][0], 0, 0, 0);
        acc[1][1] = __builtin_amdgcn_mfma_f32_16x16x32_bf16(a1, bf1, acc[1][1], 0, 0, 0);
    }

    int pt = p0 + pw;
#pragma unroll
    for (int nt = 0; nt < 2; ++nt) {
        int p = pt + nt * 16 + m;
        if (p < TV_) {
            float* o1 = f1 + n * FNS_ + p;
            float* o2 = f2 + n * FNS_ + p;
#pragma unroll
            for (int r = 0; r < 4; ++r) {
                int ol = q * 4 + r;
                o1[ol * TV_] = acc[0][nt][r] + b1[ol];
                o2[ol * TV_] = acc[1][nt][r] + b2[ol];
            }
        }
    }
}

// ---------------- gram partial: S_part[n,v1,v2] over 960 contraction rows ----------------
__global__ __launch_bounds__(256) void gram_partial(
    const float* __restrict__ f1, const float* __restrict__ f2, float* __restrict__ part) {
    __shared__ float t1[64 * 25], t2[64 * 25];
    int n = blockIdx.x, pr = blockIdx.y;   // pr in [0,5)
    int tid = threadIdx.x;
    const float* f1n = f1 + n * FNS_ + pr * 960 * 25;
    const float* f2n = f2 + n * FNS_ + pr * 960 * 25;
    int va0 = tid / 25, vb0 = tid % 25;
    int va1 = (tid + 256) / 25, vb1 = (tid + 256) % 25;
    int va2 = (tid + 512) / 25, vb2 = (tid + 512) % 25;
    float acc0 = 0.f, acc1 = 0.f, acc2 = 0.f;
    for (int tile = 0; tile < 15; ++tile) {
        __syncthreads();
        for (int j = tid; j < 1600; j += 256) {
            t1[j] = f1n[tile * 1600 + j];
            t2[j] = f2n[tile * 1600 + j];
        }
        __syncthreads();
#pragma unroll 8
        for (int rr = 0; rr < 64; ++rr) {
            const float* r1 = &t1[rr * 25];
            const float* r2 = &t2[rr * 25];
            acc0 += r1[va0] * r2[vb0];
            acc1 += r1[va1] * r2[vb1];
            acc2 += r1[va2] * r2[vb2];
        }
    }
    float* pp = part + (pr * 64 + n) * 625;
    pp[tid] = acc0;
    pp[tid + 256] = acc1;
    if (tid < 113) pp[tid + 512] = acc2;
}

// ---------------- gram finalize: sum parts, scale, column softmax ----------------
__global__ __launch_bounds__(256) void gram_finalize(
    const float* __restrict__ part, float* __restrict__ S) {
    __shared__ float sm[625];
    int n = blockIdx.x, tid = threadIdx.x;
    for (int qq = tid; qq < 625; qq += 256) {
        float s = 0.f;
#pragma unroll
        for (int p = 0; p < 5; ++p) s += part[(p * 64 + n) * 625 + qq];
        sm[qq] = s * (1.f / 4800.f);
    }
    __syncthreads();
    if (tid < 25) {
        int col = tid;
        float m = -1e30f;
#pragma unroll
        for (int r = 0; r < 25; ++r) m = fmaxf(m, sm[r * 25 + col]);
        float e[25];
        float sum = 0.f;
#pragma unroll
        for (int r = 0; r < 25; ++r) { e[r] = __expf(sm[r * 25 + col] - m); sum += e[r]; }
        float inv = 1.f / sum;
#pragma unroll
        for (int r = 0; r < 25; ++r) S[n * 625 + r * 25 + col] = e[r] * inv;
    }
}

// ---------------- fused: Ai build + z = x@Ai + y += d_w@z + d_b ----------------
__global__ __launch_bounds__(256) void fused_zd(
    const float* __restrict__ x, const float* __restrict__ amix,
    const float* __restrict__ Sab, const float* __restrict__ St, const float* __restrict__ Sst,
    const float* __restrict__ wts, const float* __restrict__ dw, const float* __restrict__ db,
    float* __restrict__ y, int first) {
    __shared__ float xs[64 * 75];   // [c][3t*25v]
    __shared__ float zs[64 * 75];
    __shared__ float aw[625];
    __shared__ float dws[4096];
    int n = blockIdx.y;
    int t0 = blockIdx.x * 3;
    int tid = threadIdx.x;
    float w5 = wts[5], w6 = wts[6], w7 = wts[7];
    for (int j = tid; j < 625; j += 256)
        aw[j] = amix[j] + w5 * Sab[n * 625 + j] + w6 * St[n * 625 + j] + w7 * Sst[n * 625 + j];
    for (int j = tid; j < 4096; j += 256) dws[j] = dw[j];
    const float* xb = x + n * CTV_ + t0 * V_;
    for (int j = tid; j < 4800; j += 256) {
        int c = j / 75, qq = j - c * 75;
        xs[j] = xb[c * TV_ + qq];
    }
    __syncthreads();
    for (int j = tid; j < 4800; j += 256) {
        int c = j / 75, qq = j - c * 75;
        int tt = qq / 25, v = qq - tt * 25;
        float acc = 0.f;
        const float* xr = &xs[c * 75 + tt * 25];
#pragma unroll
        for (int vp = 0; vp < 25; ++vp) acc += xr[vp] * aw[vp * 25 + v];
        zs[j] = acc;
    }
    __syncthreads();
    float* yb = y + n * CTV_ + t0 * V_;
    for (int j = tid; j < 4800; j += 256) {
        int o = j / 75, qq = j - o * 75;
        float acc = db[o];
        const float* dr = &dws[o * 64];
#pragma unroll 16
        for (int c = 0; c < 64; ++c) acc += dr[c] * zs[c * 75 + qq];
        float* yp = &yb[o * TV_ + qq];
        if (first) *yp = acc;
        else       *yp += acc;
    }
}

// ---------------- BN reduce: per-channel sum / sumsq ----------------
__global__ __launch_bounds__(256) void bn_reduce(const float* __restrict__ y,
                                                 float* __restrict__ stats) {
    int o = blockIdx.x;
    int partn = blockIdx.y;
    int tid = threadIdx.x;
    float s = 0.f, s2 = 0.f;
    for (int nn = partn * 8; nn < partn * 8 + 8; ++nn) {
        const float* yp = y + (nn * C_ + o) * TV_;
        for (int j = tid; j < TV_; j += 256) {
            float v = yp[j];
            s += v;
            s2 += v * v;
        }
    }
    for (int off = 32; off > 0; off >>= 1) {
        s += __shfl_down(s, off, 64);
        s2 += __shfl_down(s2, off, 64);
    }
    __shared__ float ls[8];
    int wave = tid >> 6, lane = tid & 63;
    if (lane == 0) { ls[wave] = s; ls[4 + wave] = s2; }
    __syncthreads();
    if (tid == 0) {
        atomicAdd(&stats[o], ls[0] + ls[1] + ls[2] + ls[3]);
        atomicAdd(&stats[64 + o], ls[4] + ls[5] + ls[6] + ls[7]);
    }
}

// ---------------- BN apply + residual + relu (in place on y) ----------------
__global__ __launch_bounds__(256) void bn_final(
    const float* __restrict__ x, const float* __restrict__ stats,
    const float* __restrict__ bnw, const float* __restrict__ bnb,
    float* __restrict__ y) {
    int pi = blockIdx.x * 256 + threadIdx.x;
    int o = (pi / TV_) & 63;
    const float cnt = (float)(N_ * TV_);
    float mu = stats[o] / cnt;
    float var = stats[64 + o] / cnt - mu * mu;
    float inv = rsqrtf(var + 1e-5f);
    float val = (y[pi] - mu) * inv * bnw[o] + bnb[o] + x[pi];
    y[pi] = fmaxf(val, 0.f);
}

extern "C" void kernel_launch(void* const* d_in, const int* in_sizes, int n_in,
                              void* d_out, int out_size, void* d_ws, size_t ws_size,
                              hipStream_t stream) {
    (void)in_sizes; (void)n_in; (void)out_size; (void)ws_size;
    const float* x     = (const float*)d_in[0];
    const float* wts   = (const float*)d_in[1];
    const float* A     = (const float*)d_in[2];
    const float* a_w   = (const float*)d_in[3];
    const float* a_b   = (const float*)d_in[4];
    const float* b_w   = (const float*)d_in[5];
    const float* b_b   = (const float*)d_in[6];
    const float* d_wp  = (const float*)d_in[7];
    const float* d_bp  = (const float*)d_in[8];
    const float* t1_w  = (const float*)d_in[9];
    const float* t1_b  = (const float*)d_in[10];
    const float* t2_w  = (const float*)d_in[11];
    const float* t2_b  = (const float*)d_in[12];
    const float* st11_w1 = (const float*)d_in[13];
    const float* st11_w9 = (const float*)d_in[14];
    const float* st11_b  = (const float*)d_in[15];
    const float* st12_w1 = (const float*)d_in[16];
    const float* st12_w9 = (const float*)d_in[17];
    const float* st12_b  = (const float*)d_in[18];
    const float* bn_w  = (const float*)d_in[19];
    const float* bn_b  = (const float*)d_in[20];
    float* out = (float*)d_out;

    char* ws = (char*)d_ws;
    float* amix  = (float*)(ws);              // 1875 floats
    float* stats = (float*)(ws + 8192);       // 128 floats
    float* S     = (float*)(ws + 16384);      // 3 * 40000 floats
    float* part  = (float*)(ws + 524288);     // 200000 floats
    short* wpk   = (short*)(ws + 1572864);    // up to 18432 bf16
    float* f1    = (float*)(ws + 2097152);    // 7,680,000 floats
    float* f2    = (float*)(ws + 33554432);   // 7,680,000 floats

    amix_kernel<<<1, 128, 0, stream>>>(A, wts, amix);
    hipMemsetAsync(stats, 0, 512, stream);

    auto run_pair = [&](bool nine, const float* w1, const float* bb1,
                        const float* w2, const float* bb2, float* Sdst) {
        int taps = nine ? 9 : 1;
        wprep<<<(taps * 2048 + 255) / 256, 256, 0, stream>>>(w1, w2, wpk, taps);
        if (nine)
            conv_mfma<9><<<dim3(59, 64), 256, 0, stream>>>(x, wpk, bb1, bb2, f1, f2);
        else
            conv_mfma<1><<<dim3(59, 64), 256, 0, stream>>>(x, wpk, bb1, bb2, f1, f2);
        gram_partial<<<dim3(64, 5), 256, 0, stream>>>(f1, f2, part);
        gram_finalize<<<64, 256, 0, stream>>>(part, Sdst);
    };

    for (int i = 0; i < 3; ++i) {
        run_pair(false, a_w + i * 1024, a_b + i * 16, b_w + i * 1024, b_b + i * 16, S);
        run_pair(true,  t1_w + i * 9216, t1_b + i * 16, t2_w + i * 9216, t2_b + i * 16, S + 40000);
        if (i == 1) {
            run_pair(true, st11_w9, st11_b + 16, st12_w9, st12_b + 16, S + 80000);
        } else {
            int j = (i == 0) ? 0 : 1;
            run_pair(false, st11_w1 + j * 1024, st11_b + i * 16,
                     st12_w1 + j * 1024, st12_b + i * 16, S + 80000);
        }
        fused_zd<<<dim3(100, 64), 256, 0, stream>>>(
            x, amix + i * 625, S, S + 40000, S + 80000, wts,
            d_wp + i * 4096, d_bp + i * 64, out, (i == 0) ? 1 : 0);
    }

    bn_reduce<<<dim3(64, 8), 256, 0, stream>>>(out, stats);
    bn_final<<<120000, 256, 0, stream>>>(x, stats, bn_w, bn_b, out);
}

// Round 4
// 2074.550 us; speedup vs baseline: 1.8964x; 1.5443x over previous
//
#include <hip/hip_runtime.h>

#define N_    64
#define C_    64
#define T_    300
#define V_    25
#define IC_   16
#define TV_   7500      // T*V
#define CTV_  480000    // C*T*V  (per-n x slice)
#define FNS_  120000    // IC*T*V (per-n f slice)
#define NB_   6400      // mega grid blocks (100 x 64)

typedef __attribute__((ext_vector_type(8))) short short8;
typedef __attribute__((ext_vector_type(4))) float f32x4;

static __device__ inline short f2bf(float f) {
    unsigned u = __float_as_uint(f);
    unsigned r = (u + 0x7fff + ((u >> 16) & 1)) >> 16;
    return (short)r;
}

// ---------------- A_mix: Chebyshev mix + column softmax ----------------
__global__ void amix_kernel(const float* __restrict__ A, const float* __restrict__ w,
                            float* __restrict__ amix) {
    int tid = threadIdx.x;
    if (tid >= 75) return;
    int s = tid / 25, col = tid % 25;
    const float* As = A + s * 625;
    float av[25], ch4[25];
#pragma unroll
    for (int r = 0; r < 25; ++r) {
        float a = As[r * 25 + col];
        float a2 = a * a;
        float eye = (r == col) ? 1.f : 0.f;
        av[r] = a;
        ch4[r] = 8.f * a2 * a2 - 8.f * a2 + eye;
    }
    float m = -1e30f;
#pragma unroll
    for (int r = 0; r < 25; ++r) m = fmaxf(m, ch4[r] * (1.f / 25.f));
    float e[25];
    float sum = 0.f;
#pragma unroll
    for (int r = 0; r < 25; ++r) { e[r] = __expf(ch4[r] * (1.f / 25.f) - m); sum += e[r]; }
    float inv = 1.f / sum;
    float w0 = w[0], w1 = w[1], w2 = w[2], w3 = w[3], w4 = w[4];
#pragma unroll
    for (int r = 0; r < 25; ++r) {
        float a = av[r], a2 = a * a;
        float eye = (r == col) ? 1.f : 0.f;
        amix[s * 625 + r * 25 + col] =
            w0 * a + w1 * (e[r] * inv) + w2 * ch4[r] +
            w3 * (4.f * a2 * a - 3.f * a) + w4 * (2.f * a2 - eye);
    }
}

// ---------------- weight prep: pack pair weights into A-fragment order, bf16 ----------------
__global__ void wprep(const float* __restrict__ w1, const float* __restrict__ w2,
                      short* __restrict__ wpk, int taps) {
    int idx = blockIdx.x * 256 + threadIdx.x;
    if (idx >= taps * 2048) return;
    int j = idx & 7;
    int l = (idx >> 3) & 63;
    int half = (idx >> 9) & 1;
    int kk = idx >> 10;
    int K = kk * 32 + ((l >> 4) << 3) + j;
    int c = K & 63, k = K >> 6;
    int o = l & 15;
    const float* w = half ? w2 : w1;
    wpk[idx] = f2bf(w[(o * 64 + c) * taps + k]);
}

// ---------------- dw prep: 12 m-tiles (rows R = i*64+o), K = c (64), bf16 A-frags ----------------
__global__ void dwprep(const float* __restrict__ dw, const float* __restrict__ db,
                       short* __restrict__ dwpk, float* __restrict__ db_sum) {
    int idx = blockIdx.x * 256 + threadIdx.x;
    if (idx < 12288) {
        int j = idx & 7;
        int lane = (idx >> 3) & 63;
        int kk = (idx >> 9) & 1;
        int mt = idx >> 10;
        int R = mt * 16 + (lane & 15);
        int c = kk * 32 + ((lane >> 4) << 3) + j;
        int i = R >> 6, o = R & 63;
        dwpk[idx] = f2bf(dw[i * 4096 + o * 64 + c]);
    }
    if (idx < 64) db_sum[idx] = db[idx] + db[64 + idx] + db[128 + idx];
}

// ---------------- conv pair via MFMA ----------------
template <int TAPS>
__global__ __launch_bounds__(256) void conv_mfma(
    const float* __restrict__ x, const short* __restrict__ wpk,
    const float* __restrict__ b1, const float* __restrict__ b2,
    float* __restrict__ f1, float* __restrict__ f2) {
    constexpr int HALO = (TAPS / 2) * 25;
    constexpr int ROWS = 128 + 2 * HALO;
    __shared__ __align__(16) short xs[ROWS * 72];
    int tid = threadIdx.x;
    int n = blockIdx.y;
    int p0 = blockIdx.x * 128;
    const float* xn = x + n * CTV_;
    for (int jj = tid; jj < 64 * ROWS; jj += 256) {
        int c = jj / ROWS;
        int rr = jj - c * ROWS;
        int pp = p0 - HALO + rr;
        float v = (pp >= 0 && pp < TV_) ? xn[c * TV_ + pp] : 0.f;
        xs[rr * 72 + c] = f2bf(v);
    }
    __syncthreads();

    int wave = tid >> 6, lane = tid & 63;
    int q = lane >> 4, m = lane & 15;
    int pw = wave * 32;
    f32x4 acc[2][2];
#pragma unroll
    for (int h = 0; h < 2; ++h)
#pragma unroll
        for (int nt = 0; nt < 2; ++nt) acc[h][nt] = (f32x4)(0.f);

#pragma unroll
    for (int kk = 0; kk < 2 * TAPS; ++kk) {
        int k = kk >> 1;
        int c0 = (kk & 1) * 32;
        short8 a0 = *(const short8*)(wpk + ((kk * 2 + 0) * 64 + lane) * 8);
        short8 a1 = *(const short8*)(wpk + ((kk * 2 + 1) * 64 + lane) * 8);
        int rbase = HALO + pw + m + (k - TAPS / 2) * 25;
        short8 bf0 = *(const short8*)(xs + rbase * 72 + c0 + q * 8);
        short8 bf1 = *(const short8*)(xs + (rbase + 16) * 72 + c0 + q * 8);
        acc[0][0] = __builtin_amdgcn_mfma_f32_16x16x32_bf16(a0, bf0, acc[0][0], 0, 0, 0);
        acc[0][1] = __builtin_amdgcn_mfma_f32_16x16x32_bf16(a0, bf1, acc[0][1], 0, 0, 0);
        acc[1][0] = __builtin_amdgcn_mfma_f32_16x16x32_bf16(a1, bf0, acc[1][0], 0, 0, 0);
        acc[1][1] = __builtin_amdgcn_mfma_f32_16x16x32_bf16(a1, bf1, acc[1][1], 0, 0, 0);
    }

    int pt = p0 + pw;
#pragma unroll
    for (int nt = 0; nt < 2; ++nt) {
        int p = pt + nt * 16 + m;
        if (p < TV_) {
            float* o1 = f1 + n * FNS_ + p;
            float* o2 = f2 + n * FNS_ + p;
#pragma unroll
            for (int r = 0; r < 4; ++r) {
                int ol = q * 4 + r;
                o1[ol * TV_] = acc[0][nt][r] + b1[ol];
                o2[ol * TV_] = acc[1][nt][r] + b2[ol];
            }
        }
    }
}

// ---------------- gram partial ----------------
__global__ __launch_bounds__(256) void gram_partial(
    const float* __restrict__ f1, const float* __restrict__ f2, float* __restrict__ part) {
    __shared__ float t1[64 * 25], t2[64 * 25];
    int n = blockIdx.x, pr = blockIdx.y;
    int tid = threadIdx.x;
    const float* f1n = f1 + n * FNS_ + pr * 960 * 25;
    const float* f2n = f2 + n * FNS_ + pr * 960 * 25;
    int va0 = tid / 25, vb0 = tid % 25;
    int va1 = (tid + 256) / 25, vb1 = (tid + 256) % 25;
    int va2 = (tid + 512) / 25, vb2 = (tid + 512) % 25;
    float acc0 = 0.f, acc1 = 0.f, acc2 = 0.f;
    for (int tile = 0; tile < 15; ++tile) {
        __syncthreads();
        for (int j = tid; j < 1600; j += 256) {
            t1[j] = f1n[tile * 1600 + j];
            t2[j] = f2n[tile * 1600 + j];
        }
        __syncthreads();
#pragma unroll 8
        for (int rr = 0; rr < 64; ++rr) {
            const float* r1 = &t1[rr * 25];
            const float* r2 = &t2[rr * 25];
            acc0 += r1[va0] * r2[vb0];
            acc1 += r1[va1] * r2[vb1];
            acc2 += r1[va2] * r2[vb2];
        }
    }
    float* pp = part + (pr * 64 + n) * 625;
    pp[tid] = acc0;
    pp[tid + 256] = acc1;
    if (tid < 113) pp[tid + 512] = acc2;
}

// ---------------- gram finalize ----------------
__global__ __launch_bounds__(256) void gram_finalize(
    const float* __restrict__ part, float* __restrict__ S) {
    __shared__ float sm[625];
    int n = blockIdx.x, tid = threadIdx.x;
    for (int qq = tid; qq < 625; qq += 256) {
        float s = 0.f;
#pragma unroll
        for (int p = 0; p < 5; ++p) s += part[(p * 64 + n) * 625 + qq];
        sm[qq] = s * (1.f / 4800.f);
    }
    __syncthreads();
    if (tid < 25) {
        int col = tid;
        float m = -1e30f;
#pragma unroll
        for (int r = 0; r < 25; ++r) m = fmaxf(m, sm[r * 25 + col]);
        float e[25];
        float sum = 0.f;
#pragma unroll
        for (int r = 0; r < 25; ++r) { e[r] = __expf(sm[r * 25 + col] - m); sum += e[r]; }
        float inv = 1.f / sum;
#pragma unroll
        for (int r = 0; r < 25; ++r) S[n * 625 + r * 25 + col] = e[r] * inv;
    }
}

// ---------------- mega: y = sum_i (dw_i @ x) @ Ai, all subsets, + BN partials ----------------
__global__ __launch_bounds__(256) void mega(
    const float* __restrict__ x, const float* __restrict__ amix,
    const float* __restrict__ S, const float* __restrict__ wts,
    const short* __restrict__ dwpk, const float* __restrict__ db_sum,
    float* __restrict__ out, float* __restrict__ partials) {
    __shared__ __align__(16) short xs[80 * 72];       // [p][c] bf16, stride 72
    __shared__ __align__(16) short us[3 * 64 * 104];  // [t][o][K=96 pad 104] bf16
    __shared__ __align__(16) short Aib[3 * 32 * 40];  // [i][v][vp pad 40] bf16

    int tid = threadIdx.x;
    int n = blockIdx.y;
    int t0 = blockIdx.x * 3;
    const float* xn = x + n * CTV_ + t0 * 25;

    // stage x tile (75 valid positions, pad to 80 with zeros)
    for (int jj = tid; jj < 64 * 80; jj += 256) {
        int c = jj / 80, p = jj - c * 80;
        float v = (p < 75) ? xn[c * TV_ + p] : 0.f;
        xs[p * 72 + c] = f2bf(v);
    }
    // zero us (K-pads must be 0)
    for (int jj = tid; jj < 3 * 64 * 52; jj += 256) ((int*)us)[jj] = 0;
    // build Aib (B-frag layout [i][v][vp], zero-padded)
    float w5 = wts[5], w6 = wts[6], w7 = wts[7];
    for (int jj = tid; jj < 3840; jj += 256) {
        int i = jj / 1280;
        int rem = jj - i * 1280;
        int v = rem / 40, vp = rem - v * 40;
        float val = 0.f;
        if (v < 25 && vp < 25) {
            int e = vp * 25 + v;
            val = amix[i * 625 + e]
                + w5 * S[(i * 3 + 0) * 40000 + n * 625 + e]
                + w6 * S[(i * 3 + 1) * 40000 + n * 625 + e]
                + w7 * S[(i * 3 + 2) * 40000 + n * 625 + e];
        }
        Aib[jj] = f2bf(val);
    }

    int wave = tid >> 6, lane = tid & 63;
    int q = lane >> 4, m = lane & 15;

    short8 af[3][2];
#pragma unroll
    for (int mt = 0; mt < 3; ++mt)
#pragma unroll
        for (int kk = 0; kk < 2; ++kk)
            af[mt][kk] = *(const short8*)(dwpk + ((wave * 3 + mt) * 2 + kk) * 512 + lane * 8);
    float db4[4];
#pragma unroll
    for (int r = 0; r < 4; ++r) db4[r] = db_sum[wave * 16 + q * 4 + r];

    __syncthreads();

    // ---- stage 1: u[R=i*64+o][p] = sum_c dw_i[o][c] x[c][p] ----
    f32x4 acc[3][5];
#pragma unroll
    for (int mt = 0; mt < 3; ++mt)
#pragma unroll
        for (int nt = 0; nt < 5; ++nt) acc[mt][nt] = (f32x4)(0.f);

#pragma unroll
    for (int nt = 0; nt < 5; ++nt) {
        short8 b0 = *(const short8*)(xs + (nt * 16 + m) * 72 + q * 8);
        short8 b1 = *(const short8*)(xs + (nt * 16 + m) * 72 + 32 + q * 8);
#pragma unroll
        for (int mt = 0; mt < 3; ++mt) {
            acc[mt][nt] = __builtin_amdgcn_mfma_f32_16x16x32_bf16(af[mt][0], b0, acc[mt][nt], 0, 0, 0);
            acc[mt][nt] = __builtin_amdgcn_mfma_f32_16x16x32_bf16(af[mt][1], b1, acc[mt][nt], 0, 0, 0);
        }
    }
#pragma unroll
    for (int nt = 0; nt < 5; ++nt) {
        int p = nt * 16 + m;
        if (p < 75) {
            int t = p / 25, vp = p - t * 25;
            int base = t * 6656 + vp;
#pragma unroll
            for (int mt = 0; mt < 3; ++mt) {
#pragma unroll
                for (int r = 0; r < 4; ++r) {
                    int R = wave * 48 + mt * 16 + q * 4 + r;
                    int i = R >> 6, o = R & 63;
                    us[base + o * 104 + i * 32] = f2bf(acc[mt][nt][r]);
                }
            }
        }
    }
    __syncthreads();

    // ---- stage 2: y[o][v] = sum_{i,vp} u[o][i*32+vp] * Ai[i][vp][v] ----
    short8 bfr[3][2];
#pragma unroll
    for (int i = 0; i < 3; ++i)
#pragma unroll
        for (int nt = 0; nt < 2; ++nt)
            bfr[i][nt] = *(const short8*)(Aib + (i * 32 + nt * 16 + m) * 40 + q * 8);

    float sr[4] = {0.f, 0.f, 0.f, 0.f}, s2r[4] = {0.f, 0.f, 0.f, 0.f};
    float* yb = out + n * CTV_ + t0 * 25;
#pragma unroll
    for (int t = 0; t < 3; ++t) {
        f32x4 a2[2];
        a2[0] = (f32x4)(0.f);
        a2[1] = (f32x4)(0.f);
#pragma unroll
        for (int i = 0; i < 3; ++i) {
            short8 ua = *(const short8*)(us + t * 6656 + (wave * 16 + m) * 104 + i * 32 + q * 8);
            a2[0] = __builtin_amdgcn_mfma_f32_16x16x32_bf16(ua, bfr[i][0], a2[0], 0, 0, 0);
            a2[1] = __builtin_amdgcn_mfma_f32_16x16x32_bf16(ua, bfr[i][1], a2[1], 0, 0, 0);
        }
#pragma unroll
        for (int nt = 0; nt < 2; ++nt) {
            int v = nt * 16 + m;
            if (v < 25) {
#pragma unroll
                for (int r = 0; r < 4; ++r) {
                    int o = wave * 16 + q * 4 + r;
                    float val = a2[nt][r] + db4[r];
                    yb[o * TV_ + t * 25 + v] = val;
                    sr[r] += val;
                    s2r[r] += val * val;
                }
            }
        }
    }

    int bid = blockIdx.y * 100 + blockIdx.x;
#pragma unroll
    for (int r = 0; r < 4; ++r) {
        float s = sr[r], s2 = s2r[r];
#pragma unroll
        for (int d = 1; d < 16; d <<= 1) {
            s += __shfl_xor(s, d, 64);
            s2 += __shfl_xor(s2, d, 64);
        }
        if (m == 0) {
            int o = wave * 16 + q * 4 + r;
            partials[o * NB_ + bid] = s;
            partials[(64 + o) * NB_ + bid] = s2;
        }
    }
}

// ---------------- BN stats: sum partials ----------------
__global__ __launch_bounds__(256) void bn_stats(const float* __restrict__ partials,
                                                float* __restrict__ stats) {
    int j = blockIdx.x;   // 0..127
    int tid = threadIdx.x;
    float s = 0.f;
    for (int idx = tid; idx < NB_; idx += 256) s += partials[j * NB_ + idx];
    for (int d = 32; d > 0; d >>= 1) s += __shfl_down(s, d, 64);
    __shared__ float ls[4];
    if ((tid & 63) == 0) ls[tid >> 6] = s;
    __syncthreads();
    if (tid == 0) stats[j] = ls[0] + ls[1] + ls[2] + ls[3];
}

// ---------------- BN apply + residual + relu (in place on y) ----------------
__global__ __launch_bounds__(256) void bn_final(
    const float* __restrict__ x, const float* __restrict__ stats,
    const float* __restrict__ bnw, const float* __restrict__ bnb,
    float* __restrict__ y) {
    int pi = blockIdx.x * 256 + threadIdx.x;
    int o = (pi / TV_) & 63;
    const float cnt = (float)(N_ * TV_);
    float mu = stats[o] / cnt;
    float var = stats[64 + o] / cnt - mu * mu;
    float inv = rsqrtf(var + 1e-5f);
    float val = (y[pi] - mu) * inv * bnw[o] + bnb[o] + x[pi];
    y[pi] = fmaxf(val, 0.f);
}

extern "C" void kernel_launch(void* const* d_in, const int* in_sizes, int n_in,
                              void* d_out, int out_size, void* d_ws, size_t ws_size,
                              hipStream_t stream) {
    (void)in_sizes; (void)n_in; (void)out_size; (void)ws_size;
    const float* x     = (const float*)d_in[0];
    const float* wts   = (const float*)d_in[1];
    const float* A     = (const float*)d_in[2];
    const float* a_w   = (const float*)d_in[3];
    const float* a_b   = (const float*)d_in[4];
    const float* b_w   = (const float*)d_in[5];
    const float* b_b   = (const float*)d_in[6];
    const float* d_wp  = (const float*)d_in[7];
    const float* d_bp  = (const float*)d_in[8];
    const float* t1_w  = (const float*)d_in[9];
    const float* t1_b  = (const float*)d_in[10];
    const float* t2_w  = (const float*)d_in[11];
    const float* t2_b  = (const float*)d_in[12];
    const float* st11_w1 = (const float*)d_in[13];
    const float* st11_w9 = (const float*)d_in[14];
    const float* st11_b  = (const float*)d_in[15];
    const float* st12_w1 = (const float*)d_in[16];
    const float* st12_w9 = (const float*)d_in[17];
    const float* st12_b  = (const float*)d_in[18];
    const float* bn_w  = (const float*)d_in[19];
    const float* bn_b  = (const float*)d_in[20];
    float* out = (float*)d_out;

    // ---- workspace layout (disjoint lifetimes audited) ----
    // amix      [0        , 7,500)
    // stats     [8,192    , 8,704)
    // db_sum    [12,288   , 12,544)
    // S         [16,384   , 1,456,384)   9 slabs x 160,000 B
    // wpk       [1,572,864, 1,609,728)
    // dwpk      [1,638,400, 1,662,976)
    // part      [1,703,936, 2,503,936)   NO overlap with S (bug fixed this round)
    // f1        [2,621,440, 33,341,440)
    // f2        [33,554,432, 64,274,432)
    // partials  reuses f1 region (f1 dead after last gram chain)
    char* ws = (char*)d_ws;
    float* amix   = (float*)(ws);
    float* stats  = (float*)(ws + 8192);
    float* db_sum = (float*)(ws + 12288);
    float* S      = (float*)(ws + 16384);
    short* wpk    = (short*)(ws + 1572864);
    short* dwpk   = (short*)(ws + 1638400);
    float* part   = (float*)(ws + 1703936);
    float* f1     = (float*)(ws + 2621440);
    float* f2     = (float*)(ws + 33554432);
    float* partials = (float*)(ws + 2621440);

    amix_kernel<<<1, 128, 0, stream>>>(A, wts, amix);
    dwprep<<<48, 256, 0, stream>>>(d_wp, d_bp, dwpk, db_sum);

    auto run_pair = [&](bool nine, const float* w1, const float* bb1,
                        const float* w2, const float* bb2, float* Sdst) {
        int taps = nine ? 9 : 1;
        wprep<<<(taps * 2048 + 255) / 256, 256, 0, stream>>>(w1, w2, wpk, taps);
        if (nine)
            conv_mfma<9><<<dim3(59, 64), 256, 0, stream>>>(x, wpk, bb1, bb2, f1, f2);
        else
            conv_mfma<1><<<dim3(59, 64), 256, 0, stream>>>(x, wpk, bb1, bb2, f1, f2);
        gram_partial<<<dim3(64, 5), 256, 0, stream>>>(f1, f2, part);
        gram_finalize<<<64, 256, 0, stream>>>(part, Sdst);
    };

    for (int i = 0; i < 3; ++i) {
        run_pair(false, a_w + i * 1024, a_b + i * 16, b_w + i * 1024, b_b + i * 16,
                 S + (i * 3 + 0) * 40000);
        run_pair(true,  t1_w + i * 9216, t1_b + i * 16, t2_w + i * 9216, t2_b + i * 16,
                 S + (i * 3 + 1) * 40000);
        if (i == 1) {
            run_pair(true, st11_w9, st11_b + 16, st12_w9, st12_b + 16,
                     S + (i * 3 + 2) * 40000);
        } else {
            int j = (i == 0) ? 0 : 1;
            run_pair(false, st11_w1 + j * 1024, st11_b + i * 16,
                     st12_w1 + j * 1024, st12_b + i * 16,
                     S + (i * 3 + 2) * 40000);
        }
    }

    mega<<<dim3(100, 64), 256, 0, stream>>>(x, amix, S, wts, dwpk, db_sum, out, partials);
    bn_stats<<<128, 256, 0, stream>>>(partials, stats);
    bn_final<<<120000, 256, 0, stream>>>(x, stats, bn_w, bn_b, out);
}